// Round 3
// baseline (258.997 us; speedup 1.0000x reference)
//
#include <hip/hip_runtime.h>

// ViT cls-token-only forward. B=16, C=8, D=511, DIM=2048, SEQ=512, NH=16.
// q = (cls+pos0) @ Wq + bq; r[h] = SCALE * Wk_h @ q_h;
// scores[b,h,j] = tok[b,j].r[h]; softmax; u[b,h] = sum_j p tok[b,j];
// ao = u @ Wv + bv; out = ao @ proj_w + proj_b.
//
// R11: dual-layout tok precompute; k3/k5 become pure global-read MFMA.
//  - tr_read dropped (R10 failure: semantics underdetermined from notes).
//  - k0 writes tok[b][j][d] AND tokT[b][d][j] (bf16 hi/lo) once; transpose
//    via LDS tile (row stride 72 halfwords; phase-2 lanes span d -> 2-way
//    bank access, free per m136).
//  - k3 operand-swapped: D[h][j] = sum_d r[h][d] tok[j][d] — BOTH fragments
//    d-contiguous 16-B loads. MFMA order arranged to keep fp32 accumulation
//    bitwise identical to R9's passing kernel.
//  - k5: A = p[h][j-chunk] (j-contig), B = tokT[d][j-chunk] (j-contig).
//    No LDS anywhere in k3/k5.
//  - absmax canary: math is bitwise-identical to R9 -> expect 0.00390625.

#define BB   16
#define CC   8
#define DD   511
#define DIM  2048
#define SEQ  512
#define NH   16
#define HD   128
#define W3   6144
#define SCALE 0.08838834764831845f

// workspace layout (float offsets)
#define QP_OFF   0            // 64*2048 q partials (plain)
#define G_OFF    131072       // 16 atomic gamma (zeroed by k0)
#define AO_OFF   131088       // 32768 atomic ao (zeroed by k0)
#define SCP_OFF  163856       // 4*131072 score partials (plain)
#define SCPSZ    131072
#define RB_OFF   688144       // r bf16 hi/lo: 65536 shorts (32768 floats)
#define PB_OFF   720912       // p bf16 hi/lo: 262144 shorts (131072 floats)
#define U_OFF    851984       // 524288 u fp32
#define TOKH_OFF 1376272      // tok[b][j][d] hi: 16,777,216 shorts
#define TOKL_OFF 9764880      // tok lo
#define TTH_OFF  18153488     // tokT[b][d][j] hi
#define TTL_OFF  26542096     // tokT lo
// total = 34,930,704 floats ~= 139.7 MB (ws >= 256 MB per harness fills)

typedef __attribute__((ext_vector_type(8))) short short8;
typedef __attribute__((ext_vector_type(4))) float floatx4;

static __device__ inline short bf_hi(float f) {
  return (short)(__float_as_uint(f) >> 16);          // truncate to bf16
}
static __device__ inline float bf_hif(float f) {
  return __uint_as_float(__float_as_uint(f) & 0xffff0000u);
}

#define LSTR 72   // k0 LDS row stride in halfwords (16-B aligned rows)

// K0: blocks 0..4095: tok + tokT precompute per (b, jt[64 j], dt[64 d]) tile,
// plus zeroing of G/AO/out. blocks 4096..4607: q partials (old k1).
__global__ __launch_bounds__(256) void k0_tok(
    const float* __restrict__ x, const float* __restrict__ pos,
    const float* __restrict__ cls, const float* __restrict__ qkv_w,
    const float* __restrict__ qkv_b, float* __restrict__ ws,
    float* __restrict__ out) {
  int blk = blockIdx.x, t = threadIdx.x;
  if (blk < 4096) {
    int gid = blk * 256 + t;
    if (gid < 32784) ws[G_OFF + gid] = 0.f;      // G + AO contiguous
    if (gid < BB * DIM) out[gid] = 0.f;
    int dt = blk & 31, jt = (blk >> 5) & 7, b = blk >> 8;
    __shared__ __attribute__((aligned(16))) short lh[64 * LSTR];
    __shared__ __attribute__((aligned(16))) short ll[64 * LSTR];
    short* th = (short*)(ws + TOKH_OFF);
    short* tl = (short*)(ws + TOKL_OFF);
    const size_t xb = (size_t)b * CC * DD * 256;
    // phase 1: compute f = x+pos (fp32), write tok row-major, stage LDS
#pragma unroll
    for (int rep = 0; rep < 2; ++rep) {
      int g = rep * 256 + t;                     // 0..511
      int j_loc = g >> 3, dg = g & 7;
      int j = jt * 64 + j_loc;
      int d = dt * 64 + dg * 8;
      const float* pp = pos + (size_t)j * DIM + d;
      float4 pa = *reinterpret_cast<const float4*>(pp);
      float4 pb = *reinterpret_cast<const float4*>(pp + 4);
      float4 xa, xb4;
      if (j == 0) {
        xa  = *reinterpret_cast<const float4*>(cls + d);
        xb4 = *reinterpret_cast<const float4*>(cls + d + 4);
      } else {
        const float* xr = x + xb + (size_t)(d >> 8) * DD * 256 +
                          (size_t)(j - 1) * 256 + (d & 255);
        xa  = *reinterpret_cast<const float4*>(xr);
        xb4 = *reinterpret_cast<const float4*>(xr + 4);
      }
      float f[8] = {xa.x + pa.x,  xa.y + pa.y,  xa.z + pa.z,  xa.w + pa.w,
                    xb4.x + pb.x, xb4.y + pb.y, xb4.z + pb.z, xb4.w + pb.w};
      short8 hi, lo;
#pragma unroll
      for (int i = 0; i < 8; ++i) {
        hi[i] = bf_hi(f[i]);
        lo[i] = bf_hi(f[i] - bf_hif(f[i]));      // f-hi exact, then truncate
      }
      size_t o = (size_t)(b * SEQ + j) * DIM + d;
      *reinterpret_cast<short8*>(th + o) = hi;
      *reinterpret_cast<short8*>(tl + o) = lo;
      *reinterpret_cast<short8*>(lh + j_loc * LSTR + dg * 8) = hi;
      *reinterpret_cast<short8*>(ll + j_loc * LSTR + dg * 8) = lo;
    }
    __syncthreads();
    // phase 2: transposed read from LDS, write tokT[b][d][j]
    short* tth = (short*)(ws + TTH_OFF);
    short* ttl = (short*)(ws + TTL_OFF);
#pragma unroll
    for (int rep = 0; rep < 2; ++rep) {
      int c = rep * 256 + t;                     // 0..511
      int jc = c >> 6, d_loc = c & 63;           // lanes span d -> 2-way banks
      short8 hv, lv;
#pragma unroll
      for (int i = 0; i < 8; ++i) {
        hv[i] = lh[(jc * 8 + i) * LSTR + d_loc];
        lv[i] = ll[(jc * 8 + i) * LSTR + d_loc];
      }
      size_t o = (size_t)(b * DIM + dt * 64 + d_loc) * SEQ + jt * 64 + jc * 8;
      *reinterpret_cast<short8*>(tth + o) = hv;
      *reinterpret_cast<short8*>(ttl + o) = lv;
    }
  } else {
    int bb = blk - 4096;                         // 0..511
    int nt = bb & 7, dc = bb >> 3;
    int n = nt * 256 + t;
    int d0 = dc * 32;
    float acc = (dc == 0) ? qkv_b[n] : 0.f;
#pragma unroll 8
    for (int d = d0; d < d0 + 32; ++d) {
      float t0 = cls[d] + pos[d];                // uniform -> scalar load
      acc += t0 * qkv_w[(size_t)d * W3 + n];
    }
    ws[QP_OFF + dc * DIM + n] = acc;
  }
}

// K2: r[h][d] = SCALE * (Wk[d, h-slice] . q[h-slice]); q from summing the 64
// k0 partials. Writes bf16 hi/lo r + atomic gamma. grid (16 dtile, 16 h), 128.
__global__ __launch_bounds__(128) void k2_r(
    const float* __restrict__ qkv_w, const float* __restrict__ pos,
    const float* __restrict__ cls, float* __restrict__ ws) {
  __shared__ float qs[HD];
  int h = blockIdx.y;
  int d = blockIdx.x * 128 + threadIdx.x;
  float qa = 0.f;
#pragma unroll 8
  for (int c = 0; c < 64; ++c)
    qa += ws[QP_OFF + c * DIM + h * HD + threadIdx.x];
  qs[threadIdx.x] = qa;
  __syncthreads();
  const float4* w4 = reinterpret_cast<const float4*>(
      qkv_w + (size_t)d * W3 + DIM + h * HD);
  float acc = 0.f;
#pragma unroll 8
  for (int e4 = 0; e4 < 32; ++e4) {
    float4 w = w4[e4];
    acc += qs[e4*4+0]*w.x + qs[e4*4+1]*w.y + qs[e4*4+2]*w.z + qs[e4*4+3]*w.w;
  }
  float r = acc * SCALE;
  int i = h * DIM + d;
  short* rb = (short*)(ws + RB_OFF);
  rb[i] = bf_hi(r);
  rb[NH * DIM + i] = bf_hi(r - bf_hif(r));
  float g = (cls[d] + pos[d]) * r;
  for (int m = 1; m < 64; m <<= 1) g += __shfl_xor(g, m, 64);
  if ((threadIdx.x & 63) == 0) atomicAdd(&ws[G_OFF + h], g);
}

// K3: scores via MFMA, operand-swapped: D[h][j] = sum_d r[h][d] tok[j][d].
// A-fragment = r[h=l&15][d-chunk] (RB, d-contig); B-fragment =
// tok[j = jt*16 + (l&15)][d-chunk] (row-major tok, d-contig). Plain stores
// to per-ks partial buffers. grid (8 jt2, 16 b, 4 ks), 256 thr.
__global__ __launch_bounds__(256) void k3_scores_mfma(float* __restrict__ ws) {
  int jt2 = blockIdx.x, b = blockIdx.y, ks = blockIdx.z;
  int t = threadIdx.x, w = t >> 6, l = t & 63;
  int jt = jt2 * 4 + w;
  int m16 = l & 15, kq = l >> 4;
  int j = jt * 16 + m16;                         // 0..511 (j=0 real cls row)
  const short* rh = (const short*)(ws + RB_OFF);
  const short* rl = rh + NH * DIM;
  const short* th = (const short*)(ws + TOKH_OFF);
  const short* tl = (const short*)(ws + TOKL_OFF);
  const short* ra = rh + m16 * DIM;              // r[h=m16][.]
  const short* rb = rl + m16 * DIM;
  const short* ta = th + (size_t)(b * SEQ + j) * DIM;
  const short* tb = tl + (size_t)(b * SEQ + j) * DIM;
  floatx4 acc = {0.f, 0.f, 0.f, 0.f};
#pragma unroll 4
  for (int kk = ks * 16; kk < ks * 16 + 16; ++kk) {
    int d0 = kk * 32 + kq * 8;
    short8 ahi = *reinterpret_cast<const short8*>(ra + d0);
    short8 alo = *reinterpret_cast<const short8*>(rb + d0);
    short8 bhi = *reinterpret_cast<const short8*>(ta + d0);
    short8 blo = *reinterpret_cast<const short8*>(tb + d0);
    // order matches R9 bitwise: tokhi*rhi, tokhi*rlo, toklo*rhi
    acc = __builtin_amdgcn_mfma_f32_16x16x32_bf16(ahi, bhi, acc, 0, 0, 0);
    acc = __builtin_amdgcn_mfma_f32_16x16x32_bf16(alo, bhi, acc, 0, 0, 0);
    acc = __builtin_amdgcn_mfma_f32_16x16x32_bf16(ahi, blo, acc, 0, 0, 0);
  }
  // C layout [m89]: col = l&15 = j, row = kq*4+reg = h
  float* sc = ws + SCP_OFF + (size_t)ks * SCPSZ + (size_t)b * NH * SEQ;
#pragma unroll
  for (int reg = 0; reg < 4; ++reg) {
    int h = kq * 4 + reg;
    sc[(size_t)h * SEQ + j] = acc[reg];
  }
}

// K4: softmax per (b,h): sum 4 score partials + gamma -> p bf16 hi/lo.
// grid (16 h, 16 b) x 64 thr.
__global__ __launch_bounds__(64) void k4_softmax(float* __restrict__ ws) {
  int h = blockIdx.x, b = blockIdx.y, l = threadIdx.x;
  const float* sc0 = ws + SCP_OFF + (size_t)(b * NH + h) * SEQ;
  float gam = ws[G_OFF + h];
  float s[8];
#pragma unroll
  for (int i = 0; i < 8; ++i) {
    int j = i * 64 + l;
    s[i] = sc0[j] + sc0[SCPSZ + j] + sc0[2 * SCPSZ + j] + sc0[3 * SCPSZ + j];
  }
  if (l == 0) s[0] = gam;                        // j=0: use fp32-path gamma
  float mx = s[0];
#pragma unroll
  for (int i = 1; i < 8; ++i) mx = fmaxf(mx, s[i]);
  for (int m = 1; m < 64; m <<= 1) mx = fmaxf(mx, __shfl_xor(mx, m, 64));
  float e[8], sum = 0.f;
#pragma unroll
  for (int i = 0; i < 8; ++i) { e[i] = __expf(s[i] - mx); sum += e[i]; }
  for (int m = 1; m < 64; m <<= 1) sum += __shfl_xor(sum, m, 64);
  float inv = 1.f / sum;
  short* ph = (short*)(ws + PB_OFF);
  short* pl = ph + NH * SEQ * BB;
#pragma unroll
  for (int i = 0; i < 8; ++i) {
    float p = e[i] * inv;
    int j = i * 64 + l;
    ph[(b * NH + h) * SEQ + j] = bf_hi(p);
    pl[(b * NH + h) * SEQ + j] = bf_hi(p - bf_hif(p));
  }
}

// K5: u[b][h][d] = sum_j p[h][j] tok[j][d] via MFMA. A = p[h=l&15][j-chunk]
// (PB, j-contig); B = tokT[d = dt*64+w*16+(l&15)][j-chunk] (j-contig).
// Pure global reads, no LDS. grid (32 dt, 16 b), 256 thr.
__global__ __launch_bounds__(256) void k5_pv_mfma(float* __restrict__ ws) {
  int dt = blockIdx.x, b = blockIdx.y, t = threadIdx.x;
  int w = t >> 6, l = t & 63;
  int m16 = l & 15, kq = l >> 4;
  int dcol = dt * 64 + w * 16 + m16;
  const short* ph = (const short*)(ws + PB_OFF);
  const short* pl = ph + NH * SEQ * BB;
  const short* tth = (const short*)(ws + TTH_OFF);
  const short* ttl = (const short*)(ws + TTL_OFF);
  const short* pa = ph + (size_t)(b * NH + m16) * SEQ;
  const short* pb = pl + (size_t)(b * NH + m16) * SEQ;
  const short* va = tth + (size_t)(b * DIM + dcol) * SEQ;
  const short* vb = ttl + (size_t)(b * DIM + dcol) * SEQ;
  floatx4 acc = {0.f, 0.f, 0.f, 0.f};
#pragma unroll 4
  for (int kk = 0; kk < 16; ++kk) {
    int j0 = kk * 32 + kq * 8;
    short8 phi = *reinterpret_cast<const short8*>(pa + j0);
    short8 plo = *reinterpret_cast<const short8*>(pb + j0);
    short8 thi = *reinterpret_cast<const short8*>(va + j0);
    short8 tlo = *reinterpret_cast<const short8*>(vb + j0);
    acc = __builtin_amdgcn_mfma_f32_16x16x32_bf16(phi, thi, acc, 0, 0, 0);
    acc = __builtin_amdgcn_mfma_f32_16x16x32_bf16(phi, tlo, acc, 0, 0, 0);
    acc = __builtin_amdgcn_mfma_f32_16x16x32_bf16(plo, thi, acc, 0, 0, 0);
  }
  // C: col(d) = l&15, row(h) = kq*4+reg
  float* ub = ws + U_OFF + (size_t)b * NH * DIM + dcol;
#pragma unroll
  for (int reg = 0; reg < 4; ++reg)
    ub[(size_t)(kq * 4 + reg) * DIM] = acc[reg];
}

// K6: ao[b][m] += sum over 32-d chunk of u[b][h][d]*Wv[d][4096+m] (+bv).
// grid (8 nt, 64 dc). (unchanged)
__global__ __launch_bounds__(256) void k6_ao(
    const float* __restrict__ qkv_w, const float* __restrict__ qkv_b,
    float* __restrict__ ws) {
  int nt = blockIdx.x, dc = blockIdx.y, t = threadIdx.x;
  int m = nt * 256 + t;
  int h0 = nt * 2;
  int d0 = dc * 32;
  __shared__ float us[2][32][20];
  for (int i = t; i < 2 * 32 * BB; i += 256) {
    int dd = i & 31, b = (i >> 5) & 15, hh = i >> 9;
    us[hh][dd][b] = ws[U_OFF + (size_t)(b * NH + h0 + hh) * DIM + d0 + dd];
  }
  __syncthreads();
  int hl = t >> 7;
  float acc[BB];
#pragma unroll
  for (int b = 0; b < BB; ++b) acc[b] = 0.f;
  const float* wcol = qkv_w + (size_t)d0 * W3 + 2 * DIM + m;
#pragma unroll 4
  for (int dd = 0; dd < 32; ++dd) {
    float w = wcol[(size_t)dd * W3];
    const float4* u4 = reinterpret_cast<const float4*>(&us[hl][dd][0]);
    float4 u0 = u4[0], u1 = u4[1], u2 = u4[2], u3 = u4[3];
    acc[0]  += u0.x * w; acc[1]  += u0.y * w; acc[2]  += u0.z * w; acc[3]  += u0.w * w;
    acc[4]  += u1.x * w; acc[5]  += u1.y * w; acc[6]  += u1.z * w; acc[7]  += u1.w * w;
    acc[8]  += u2.x * w; acc[9]  += u2.y * w; acc[10] += u2.z * w; acc[11] += u2.w * w;
    acc[12] += u3.x * w; acc[13] += u3.y * w; acc[14] += u3.z * w; acc[15] += u3.w * w;
  }
  float bias = (dc == 0) ? qkv_b[2 * DIM + m] : 0.f;
#pragma unroll
  for (int b = 0; b < BB; ++b)
    atomicAdd(&ws[AO_OFF + b * DIM + m], acc[b] + bias);
}

// K7: out[b][n] += sum over 32-m chunk of ao[b][m]*proj_w[m][n] (+pb).
// grid (8 nt, 64 mc). (unchanged)
__global__ __launch_bounds__(256) void k7_out(
    const float* __restrict__ proj_w, const float* __restrict__ proj_b,
    const float* __restrict__ ws, float* __restrict__ out) {
  int nt = blockIdx.x, mc = blockIdx.y, t = threadIdx.x;
  int n = nt * 256 + t;
  int m0 = mc * 32;
  __shared__ float as[32][20];
  for (int i = t; i < 32 * BB; i += 256) {
    int mm = i & 31, b = i >> 5;
    as[mm][b] = ws[AO_OFF + b * DIM + m0 + mm];
  }
  __syncthreads();
  float acc[BB];
#pragma unroll
  for (int b = 0; b < BB; ++b) acc[b] = 0.f;
  const float* wcol = proj_w + (size_t)m0 * DIM + n;
#pragma unroll 4
  for (int mm = 0; mm < 32; ++mm) {
    float w = wcol[(size_t)mm * DIM];
    const float4* a4 = reinterpret_cast<const float4*>(&as[mm][0]);
    float4 a0 = a4[0], a1 = a4[1], a2 = a4[2], a3 = a4[3];
    acc[0]  += a0.x * w; acc[1]  += a0.y * w; acc[2]  += a0.z * w; acc[3]  += a0.w * w;
    acc[4]  += a1.x * w; acc[5]  += a1.y * w; acc[6]  += a1.z * w; acc[7]  += a1.w * w;
    acc[8]  += a2.x * w; acc[9]  += a2.y * w; acc[10] += a2.z * w; acc[11] += a2.w * w;
    acc[12] += a3.x * w; acc[13] += a3.y * w; acc[14] += a3.z * w; acc[15] += a3.w * w;
  }
  float bias = (mc == 0) ? proj_b[n] : 0.f;
#pragma unroll
  for (int b = 0; b < BB; ++b)
    atomicAdd(&out[b * DIM + n], acc[b] + bias);
}

extern "C" void kernel_launch(void* const* d_in, const int* in_sizes, int n_in,
                              void* d_out, int out_size, void* d_ws, size_t ws_size,
                              hipStream_t stream) {
  const float* x      = (const float*)d_in[0];
  const float* pos    = (const float*)d_in[1];
  const float* cls    = (const float*)d_in[2];
  const float* qkv_w  = (const float*)d_in[3];
  const float* qkv_b  = (const float*)d_in[4];
  const float* proj_w = (const float*)d_in[5];
  const float* proj_b = (const float*)d_in[6];
  float* ws  = (float*)d_ws;
  float* out = (float*)d_out;

  k0_tok        <<<dim3(4608),      256, 0, stream>>>(x, pos, cls, qkv_w, qkv_b, ws, out);
  k2_r          <<<dim3(16, 16),    128, 0, stream>>>(qkv_w, pos, cls, ws);
  k3_scores_mfma<<<dim3(8, 16, 4),  256, 0, stream>>>(ws);
  k4_softmax    <<<dim3(16, 16),     64, 0, stream>>>(ws);
  k5_pv_mfma    <<<dim3(32, 16),    256, 0, stream>>>(ws);
  k6_ao         <<<dim3(8, 64),     256, 0, stream>>>(qkv_w, qkv_b, ws);
  k7_out        <<<dim3(8, 64),     256, 0, stream>>>(proj_w, proj_b, ws, out);
}